// Round 1
// baseline (111.809 us; speedup 1.0000x reference)
//
#include <hip/hip_runtime.h>
#include <stdint.h>

// QuantLinear eval forward.
// B=524288 rows, IN_DIM=16, OUT_DIM=32, 4 chunks of 4.
// out[b,o] = scale * sum_c( round(yP_c/15) - round(yM_c/15) ) + InMin*sum_j sign(w[o,j])
// where yP_c = dot(q[b, 4c:4c+4], relu(sign(w))[o, 4c:4c+4]), q = clip(rint((x-InMin)/scale*15),0,15)

#if __has_builtin(__builtin_amdgcn_sdot4)
#define HAVE_SDOT4 1
#else
#define HAVE_SDOT4 0
#endif

__device__ __forceinline__ int dot7(uint32_t q, uint32_t m) {
#if HAVE_SDOT4
    // bytes of q in [0,15], bytes of m in {0,1}; signed==unsigned here. acc init = 7.
    return __builtin_amdgcn_sdot4((int)q, (int)m, 7, false);
#else
    // m has 0xFF bytes; mask then horizontal byte-sum via multiply (no cross-byte carry: sums <= 60)
    return (int)(((q & m) * 0x01010101u) >> 24) + 7;
#endif
}

// round(y/15) for y in [0,60], given y7 = y+7: exact via magic multiply (no ties exist).
__device__ __forceinline__ int r15(int y7) {
    return (int)(((uint32_t)y7 * 274u) >> 12);
}

__global__ __launch_bounds__(256) void qlin_kernel(
    const float* __restrict__ in, const float* __restrict__ wgt,
    const float* __restrict__ pmin, const float* __restrict__ pmax,
    float* __restrict__ out, int nrows)
{
    __shared__ uint4 smask[64];   // [o][2]: {P masks c0..c3} , {M masks c0..c3}, packed bytes
    __shared__ float sbias[32];

    const int t = threadIdx.x;
    const float InMin = pmin[0];
    const float InMax = pmax[0];
    const float scale = __fsub_rn(InMax, InMin);

    const uint32_t MASKBYTE = HAVE_SDOT4 ? 1u : 0xFFu;

    // --- build weight sign masks cooperatively (256 threads -> 256 mask words) ---
    {
        int o = t >> 3, k = t & 7, c = k & 3, isM = k >> 2;
        const float* wrow = wgt + o * 16 + c * 4;
        uint32_t m = 0;
#pragma unroll
        for (int j = 0; j < 4; ++j) {
            float v = wrow[j];
            bool sel = isM ? (v < 0.0f) : (v > 0.0f);
            if (sel) m |= MASKBYTE << (8 * j);
        }
        ((uint32_t*)smask)[o * 8 + isM * 4 + c] = m;
    }
    __syncthreads();
    if (t < 32) {
        const uint32_t* mo = (const uint32_t*)smask + t * 8;
        int s = 0;
#pragma unroll
        for (int c = 0; c < 4; ++c)
            s += __popc(mo[c]) - __popc(mo[4 + c]);
        if (!HAVE_SDOT4) s /= 8;          // 0xFF bytes count 8 bits each
        sbias[t] = __fmul_rn(InMin, (float)s);   // bias[o] = InMin * sum_j sign(w[o,j])
    }
    __syncthreads();

    const int r = blockIdx.x * 256 + t;
    if (r >= nrows) return;

    // --- quantize the 16 inputs of this row, pack 4 per u32 ---
    const float4* inrow = (const float4*)in + (size_t)r * 4;
    const bool unit = (scale == 1.0f);
    uint32_t qp[4];
#pragma unroll
    for (int c = 0; c < 4; ++c) {
        float4 f = inrow[c];
        float e[4] = { f.x, f.y, f.z, f.w };
        uint32_t pk = 0;
#pragma unroll
        for (int j = 0; j < 4; ++j) {
            float d  = __fsub_rn(e[j], InMin);
            float sd = unit ? d : __fdiv_rn(d, scale);   // exact-match ref: (x-min)/scale
            float v  = __fmul_rn(sd, 15.0f);             // ... * 15
            float rr = rintf(v);                         // half-even, same as np.round
            rr = fminf(fmaxf(rr, 0.0f), 15.0f);          // clip(.,0,15)
            pk |= ((uint32_t)(int)rr) << (8 * j);
        }
        qp[c] = pk;
    }

    // --- 32 outputs: per (o,c), two masked byte-dots + exact integer rounding ---
    float* orow = out + (size_t)r * 32;
#pragma unroll 2
    for (int og = 0; og < 8; ++og) {
        float res[4];
#pragma unroll
        for (int i = 0; i < 4; ++i) {
            int o = og * 4 + i;
            uint4 MP = smask[o * 2 + 0];   // uniform LDS address -> broadcast
            uint4 MM = smask[o * 2 + 1];
            int acc = 0;
            acc += r15(dot7(qp[0], MP.x)) - r15(dot7(qp[0], MM.x));
            acc += r15(dot7(qp[1], MP.y)) - r15(dot7(qp[1], MM.y));
            acc += r15(dot7(qp[2], MP.z)) - r15(dot7(qp[2], MM.z));
            acc += r15(dot7(qp[3], MP.w)) - r15(dot7(qp[3], MM.w));
            res[i] = __fadd_rn(__fmul_rn((float)acc, scale), sbias[o]);
        }
        *(float4*)(orow + og * 4) = make_float4(res[0], res[1], res[2], res[3]);
    }
}

extern "C" void kernel_launch(void* const* d_in, const int* in_sizes, int n_in,
                              void* d_out, int out_size, void* d_ws, size_t ws_size,
                              hipStream_t stream) {
    (void)n_in; (void)d_ws; (void)ws_size; (void)out_size;
    const float* in  = (const float*)d_in[0];
    const float* wgt = (const float*)d_in[1];
    const float* mn  = (const float*)d_in[2];
    const float* mx  = (const float*)d_in[3];
    float* out = (float*)d_out;
    const int nrows = in_sizes[0] / 16;     // 524288
    const int blocks = (nrows + 255) / 256; // 2048
    qlin_kernel<<<blocks, 256, 0, stream>>>(in, wgt, mn, mx, out, nrows);
}

// Round 2
// 107.527 us; speedup vs baseline: 1.0398x; 1.0398x over previous
//
#include <hip/hip_runtime.h>
#include <stdint.h>

// QuantLinear eval forward — wave-coalesced version.
// B=524288 rows, IN_DIM=16 (64B/row), OUT_DIM=32 (128B/row), 4 chunks of 4.
// Per wave iteration: 16 rows. Lane l loads float4 #l of the 16-row input slab
// (coalesced 1KB), quantizes 4 elems -> 1 packed q-word (row l>>2, chunk l&3).
// 8 shuffles give lane l the 4 q-words of rows k*8+(l>>3), k=0,1.
// Lane l computes outputs (l&7)*4..+3 for those rows -> two contiguous 1KB
// wave stores. All integer math exact (absmax 0 verified in round 1).

#if __has_builtin(__builtin_amdgcn_sdot4)
#define HAVE_SDOT4 1
#else
#define HAVE_SDOT4 0
#endif

__device__ __forceinline__ int dot7(uint32_t q, uint32_t m) {
#if HAVE_SDOT4
    // bytes of q in [0,15], bytes of m in {0,1}; acc init = 7 (for the +7 of r15)
    return __builtin_amdgcn_sdot4((int)q, (int)m, 7, false);
#else
    // m has 0xFF bytes; horizontal byte-sum via multiply (sums <= 60, no carry)
    return (int)(((q & m) * 0x01010101u) >> 24) + 7;
#endif
}

// round(y/15) for y in [0,60], given y7 = y+7: exact via magic multiply (no ties).
__device__ __forceinline__ int r15(int y7) {
    return (int)(((uint32_t)y7 * 274u) >> 12);
}

__global__ __launch_bounds__(256, 6) void qlin_kernel(
    const float* __restrict__ in, const float* __restrict__ wgt,
    const float* __restrict__ pmin, const float* __restrict__ pmax,
    float* __restrict__ out, int nrows)
{
    __shared__ uint4 smask[64];                 // [o][{P,M}] : 4 packed byte-masks each
    __shared__ __align__(16) float sbias[32];

    const int t = threadIdx.x;
    const float InMin = pmin[0];
    const float InMax = pmax[0];
    const float scale = __fsub_rn(InMax, InMin);

    const uint32_t MASKBYTE = HAVE_SDOT4 ? 1u : 0xFFu;

    // --- build weight sign masks cooperatively (256 threads -> 256 mask words) ---
    {
        int o = t >> 3, k = t & 7, c = k & 3, isM = k >> 2;
        const float* wrow = wgt + o * 16 + c * 4;
        uint32_t m = 0;
#pragma unroll
        for (int j = 0; j < 4; ++j) {
            float v = wrow[j];
            bool sel = isM ? (v < 0.0f) : (v > 0.0f);
            if (sel) m |= MASKBYTE << (8 * j);
        }
        ((uint32_t*)smask)[o * 8 + isM * 4 + c] = m;
    }
    __syncthreads();
    if (t < 32) {
        const uint32_t* mo = (const uint32_t*)smask + t * 8;
        int s = 0;
#pragma unroll
        for (int c = 0; c < 4; ++c)
            s += __popc(mo[c]) - __popc(mo[4 + c]);
        if (!HAVE_SDOT4) s /= 8;                 // 0xFF bytes count 8 bits each
        sbias[t] = __fmul_rn(InMin, (float)s);   // bias[o] = InMin * sum_j sign(w[o,j])
    }
    __syncthreads();

    const int lane = t & 63;
    const int ogrp = lane & 7;                   // which 4-output group this lane owns
    const int rsel = lane >> 3;                  // row-within-8 this lane owns
    const int srcb = rsel << 2;                  // shuffle source base

    // hoist masks + bias for this lane's 4 outputs into registers (loop-invariant)
    const uint4 MP0 = smask[(ogrp * 4 + 0) * 2], MM0 = smask[(ogrp * 4 + 0) * 2 + 1];
    const uint4 MP1 = smask[(ogrp * 4 + 1) * 2], MM1 = smask[(ogrp * 4 + 1) * 2 + 1];
    const uint4 MP2 = smask[(ogrp * 4 + 2) * 2], MM2 = smask[(ogrp * 4 + 2) * 2 + 1];
    const uint4 MP3 = smask[(ogrp * 4 + 3) * 2], MM3 = smask[(ogrp * 4 + 3) * 2 + 1];
    const float4 bias = *(const float4*)(sbias + ogrp * 4);

    const bool unit = (scale == 1.0f);
    const int gw = blockIdx.x * (256 >> 6) + (t >> 6);   // global wave id
    const int nw = gridDim.x * (256 >> 6);

    for (int R = gw * 16; R < nrows; R += nw * 16) {
        // --- coalesced 1KB wave load: lane l -> row R+(l>>2), chunk l&3 ---
        const float4 f = *((const float4*)in + (size_t)R * 4 + lane);

        // --- quantize 4 elems, pack into 1 word (bit-exact vs reference) ---
        float e[4] = { f.x, f.y, f.z, f.w };
        uint32_t qw = 0;
#pragma unroll
        for (int j = 0; j < 4; ++j) {
            float d  = __fsub_rn(e[j], InMin);
            float sd = unit ? d : __fdiv_rn(d, scale);
            float v  = __fmul_rn(sd, 15.0f);
            float rr = rintf(v);
            rr = fminf(fmaxf(rr, 0.0f), 15.0f);
            qw |= ((uint32_t)(int)rr) << (8 * j);
        }

        // --- redistribute q-words: lane l needs rows k*8+rsel, chunks 0..3 ---
        const uint32_t qA0 = __shfl(qw, srcb + 0, 64);
        const uint32_t qA1 = __shfl(qw, srcb + 1, 64);
        const uint32_t qA2 = __shfl(qw, srcb + 2, 64);
        const uint32_t qA3 = __shfl(qw, srcb + 3, 64);
        const uint32_t qB0 = __shfl(qw, 32 + srcb + 0, 64);
        const uint32_t qB1 = __shfl(qw, 32 + srcb + 1, 64);
        const uint32_t qB2 = __shfl(qw, 32 + srcb + 2, 64);
        const uint32_t qB3 = __shfl(qw, 32 + srcb + 3, 64);

        float* p0 = out + (size_t)(R + rsel) * 32 + (ogrp << 2);

#define ROWCOMP(q0, q1, q2, q3, dst)                                        \
        {                                                                   \
            int a0 = r15(dot7(q0, MP0.x)) - r15(dot7(q0, MM0.x))            \
                   + r15(dot7(q1, MP0.y)) - r15(dot7(q1, MM0.y))            \
                   + r15(dot7(q2, MP0.z)) - r15(dot7(q2, MM0.z))            \
                   + r15(dot7(q3, MP0.w)) - r15(dot7(q3, MM0.w));           \
            int a1 = r15(dot7(q0, MP1.x)) - r15(dot7(q0, MM1.x))            \
                   + r15(dot7(q1, MP1.y)) - r15(dot7(q1, MM1.y))            \
                   + r15(dot7(q2, MP1.z)) - r15(dot7(q2, MM1.z))            \
                   + r15(dot7(q3, MP1.w)) - r15(dot7(q3, MM1.w));           \
            int a2 = r15(dot7(q0, MP2.x)) - r15(dot7(q0, MM2.x))            \
                   + r15(dot7(q1, MP2.y)) - r15(dot7(q1, MM2.y))            \
                   + r15(dot7(q2, MP2.z)) - r15(dot7(q2, MM2.z))            \
                   + r15(dot7(q3, MP2.w)) - r15(dot7(q3, MM2.w));           \
            int a3 = r15(dot7(q0, MP3.x)) - r15(dot7(q0, MM3.x))            \
                   + r15(dot7(q1, MP3.y)) - r15(dot7(q1, MM3.y))            \
                   + r15(dot7(q2, MP3.z)) - r15(dot7(q2, MM3.z))            \
                   + r15(dot7(q3, MP3.w)) - r15(dot7(q3, MM3.w));           \
            float4 res;                                                     \
            res.x = __fadd_rn(__fmul_rn((float)a0, scale), bias.x);         \
            res.y = __fadd_rn(__fmul_rn((float)a1, scale), bias.y);         \
            res.z = __fadd_rn(__fmul_rn((float)a2, scale), bias.z);         \
            res.w = __fadd_rn(__fmul_rn((float)a3, scale), bias.w);         \
            *(float4*)(dst) = res;                                          \
        }

        ROWCOMP(qA0, qA1, qA2, qA3, p0);             // rows R   .. R+7   (1KB contiguous)
        ROWCOMP(qB0, qB1, qB2, qB3, p0 + 8 * 32);    // rows R+8 .. R+15  (1KB contiguous)
#undef ROWCOMP
    }
}

extern "C" void kernel_launch(void* const* d_in, const int* in_sizes, int n_in,
                              void* d_out, int out_size, void* d_ws, size_t ws_size,
                              hipStream_t stream) {
    (void)n_in; (void)d_ws; (void)ws_size; (void)out_size;
    const float* in  = (const float*)d_in[0];
    const float* wgt = (const float*)d_in[1];
    const float* mn  = (const float*)d_in[2];
    const float* mx  = (const float*)d_in[3];
    float* out = (float*)d_out;
    const int nrows = in_sizes[0] / 16;     // 524288
    const int blocks = 2048;                // 8192 waves x 16 rows x 4 iters
    qlin_kernel<<<blocks, 256, 0, stream>>>(in, wgt, mn, mx, out, nrows);
}

// Round 3
// 106.316 us; speedup vs baseline: 1.0517x; 1.0114x over previous
//
#include <hip/hip_runtime.h>
#include <stdint.h>

// QuantLinear eval forward — straight-line 4-slab version.
// B=524288 rows, IN_DIM=16 (64B/row), OUT_DIM=32 (128B/row), 4 chunks of 4.
// Each wave owns 64 contiguous rows = 4 slabs of 16. All 4 slab loads (1KB
// coalesced each) are issued up-front so the LDS mask build + barriers run
// under the HBM latency; per slab: quantize -> 8 wave-local shuffles ->
// integer dot/round compute -> two contiguous 1KB wave stores.
// Integer math path identical to rounds 1-2 (absmax 0).

#if __has_builtin(__builtin_amdgcn_sdot4)
#define HAVE_SDOT4 1
#else
#define HAVE_SDOT4 0
#endif

__device__ __forceinline__ int dot7(uint32_t q, uint32_t m) {
#if HAVE_SDOT4
    // bytes of q in [0,15], bytes of m in {0,1}; acc init = 7 (for the +7 of r15)
    return __builtin_amdgcn_sdot4((int)q, (int)m, 7, false);
#else
    // m has 0xFF bytes; horizontal byte-sum via multiply (sums <= 60, no carry)
    return (int)(((q & m) * 0x01010101u) >> 24) + 7;
#endif
}

// round(y/15) for y in [0,60], given y7 = y+7: exact via magic multiply (no ties).
__device__ __forceinline__ int r15(int y7) {
    return (int)(((uint32_t)y7 * 274u) >> 12);
}

__global__ __launch_bounds__(256) void qlin_kernel(
    const float* __restrict__ in, const float* __restrict__ wgt,
    const float* __restrict__ pmin, const float* __restrict__ pmax,
    float* __restrict__ out, int nrows)
{
    __shared__ uint4 smask[64];                 // [o][{P,M}] : 4 packed byte-masks each
    __shared__ __align__(16) float sbias[32];

    const int t = threadIdx.x;
    const int lane = t & 63;
    const int wave = (blockIdx.x << 2) + (t >> 6);   // global wave id, 64 rows each
    const size_t R0 = (size_t)wave * 64;

    // --- issue all 4 slab loads NOW; mask build + barriers hide the latency ---
    const float4* inp = (const float4*)in + R0 * 4 + lane;
    float4 f0, f1, f2, f3;
    const bool live = (long)R0 < (long)nrows;        // full grid covers exactly
    if (live) {
        f0 = inp[0];
        f1 = inp[64];
        f2 = inp[128];
        f3 = inp[192];
    }

    const float InMin = pmin[0];
    const float InMax = pmax[0];
    const float scale = __fsub_rn(InMax, InMin);

    const uint32_t MASKBYTE = HAVE_SDOT4 ? 1u : 0xFFu;

    // --- build weight sign masks cooperatively (256 threads -> 256 mask words) ---
    {
        int o = t >> 3, k = t & 7, c = k & 3, isM = k >> 2;
        const float* wrow = wgt + o * 16 + c * 4;
        uint32_t m = 0;
#pragma unroll
        for (int j = 0; j < 4; ++j) {
            float v = wrow[j];
            bool sel = isM ? (v < 0.0f) : (v > 0.0f);
            if (sel) m |= MASKBYTE << (8 * j);
        }
        ((uint32_t*)smask)[o * 8 + isM * 4 + c] = m;
    }
    __syncthreads();
    if (t < 32) {
        const uint32_t* mo = (const uint32_t*)smask + t * 8;
        int s = 0;
#pragma unroll
        for (int c = 0; c < 4; ++c)
            s += __popc(mo[c]) - __popc(mo[4 + c]);
        if (!HAVE_SDOT4) s /= 8;                 // 0xFF bytes count 8 bits each
        sbias[t] = __fmul_rn(InMin, (float)s);   // bias[o] = InMin * sum_j sign(w[o,j])
    }
    __syncthreads();

    if (!live) return;

    const int ogrp = lane & 7;                   // which 4-output group this lane owns
    const int rsel = lane >> 3;                  // row-within-8 this lane owns
    const int srcb = rsel << 2;                  // shuffle source base

    // hoist masks + bias for this lane's 4 outputs into registers
    const uint4 MP0 = smask[(ogrp * 4 + 0) * 2], MM0 = smask[(ogrp * 4 + 0) * 2 + 1];
    const uint4 MP1 = smask[(ogrp * 4 + 1) * 2], MM1 = smask[(ogrp * 4 + 1) * 2 + 1];
    const uint4 MP2 = smask[(ogrp * 4 + 2) * 2], MM2 = smask[(ogrp * 4 + 2) * 2 + 1];
    const uint4 MP3 = smask[(ogrp * 4 + 3) * 2], MM3 = smask[(ogrp * 4 + 3) * 2 + 1];
    const float4 bias = *(const float4*)(sbias + ogrp * 4);

    const bool unit = (scale == 1.0f);

#define QUANT(F, QW)                                                        \
    {                                                                       \
        float e[4] = { F.x, F.y, F.z, F.w };                                \
        uint32_t pk = 0;                                                    \
        _Pragma("unroll")                                                   \
        for (int j = 0; j < 4; ++j) {                                       \
            float d  = __fsub_rn(e[j], InMin);                              \
            float sd = unit ? d : __fdiv_rn(d, scale);                      \
            float v  = __fmul_rn(sd, 15.0f);                                \
            float rr = rintf(v);                                            \
            rr = fminf(fmaxf(rr, 0.0f), 15.0f);                             \
            pk |= ((uint32_t)(int)rr) << (8 * j);                           \
        }                                                                   \
        QW = pk;                                                            \
    }

#define ROWCOMP(q0, q1, q2, q3, dst)                                        \
        {                                                                   \
            int a0 = r15(dot7(q0, MP0.x)) - r15(dot7(q0, MM0.x))            \
                   + r15(dot7(q1, MP0.y)) - r15(dot7(q1, MM0.y))            \
                   + r15(dot7(q2, MP0.z)) - r15(dot7(q2, MM0.z))            \
                   + r15(dot7(q3, MP0.w)) - r15(dot7(q3, MM0.w));           \
            int a1 = r15(dot7(q0, MP1.x)) - r15(dot7(q0, MM1.x))            \
                   + r15(dot7(q1, MP1.y)) - r15(dot7(q1, MM1.y))            \
                   + r15(dot7(q2, MP1.z)) - r15(dot7(q2, MM1.z))            \
                   + r15(dot7(q3, MP1.w)) - r15(dot7(q3, MM1.w));           \
            int a2 = r15(dot7(q0, MP2.x)) - r15(dot7(q0, MM2.x))            \
                   + r15(dot7(q1, MP2.y)) - r15(dot7(q1, MM2.y))            \
                   + r15(dot7(q2, MP2.z)) - r15(dot7(q2, MM2.z))            \
                   + r15(dot7(q3, MP2.w)) - r15(dot7(q3, MM2.w));           \
            int a3 = r15(dot7(q0, MP3.x)) - r15(dot7(q0, MM3.x))            \
                   + r15(dot7(q1, MP3.y)) - r15(dot7(q1, MM3.y))            \
                   + r15(dot7(q2, MP3.z)) - r15(dot7(q2, MM3.z))            \
                   + r15(dot7(q3, MP3.w)) - r15(dot7(q3, MM3.w));           \
            float4 res;                                                     \
            res.x = __fadd_rn(__fmul_rn((float)a0, scale), bias.x);         \
            res.y = __fadd_rn(__fmul_rn((float)a1, scale), bias.y);         \
            res.z = __fadd_rn(__fmul_rn((float)a2, scale), bias.z);         \
            res.w = __fadd_rn(__fmul_rn((float)a3, scale), bias.w);         \
            *(float4*)(dst) = res;                                          \
        }

#define SLAB(F, K)                                                          \
    {                                                                       \
        uint32_t qw;                                                        \
        QUANT(F, qw);                                                       \
        const uint32_t qA0 = __shfl(qw, srcb + 0, 64);                      \
        const uint32_t qA1 = __shfl(qw, srcb + 1, 64);                      \
        const uint32_t qA2 = __shfl(qw, srcb + 2, 64);                      \
        const uint32_t qA3 = __shfl(qw, srcb + 3, 64);                      \
        const uint32_t qB0 = __shfl(qw, 32 + srcb + 0, 64);                 \
        const uint32_t qB1 = __shfl(qw, 32 + srcb + 1, 64);                 \
        const uint32_t qB2 = __shfl(qw, 32 + srcb + 2, 64);                 \
        const uint32_t qB3 = __shfl(qw, 32 + srcb + 3, 64);                 \
        float* p0 = out + (R0 + (size_t)(K)*16 + rsel) * 32 + (ogrp << 2);  \
        ROWCOMP(qA0, qA1, qA2, qA3, p0);                                    \
        ROWCOMP(qB0, qB1, qB2, qB3, p0 + 8 * 32);                           \
    }

    SLAB(f0, 0)
    SLAB(f1, 1)
    SLAB(f2, 2)
    SLAB(f3, 3)

#undef SLAB
#undef ROWCOMP
#undef QUANT
}

extern "C" void kernel_launch(void* const* d_in, const int* in_sizes, int n_in,
                              void* d_out, int out_size, void* d_ws, size_t ws_size,
                              hipStream_t stream) {
    (void)n_in; (void)d_ws; (void)ws_size; (void)out_size;
    const float* in  = (const float*)d_in[0];
    const float* wgt = (const float*)d_in[1];
    const float* mn  = (const float*)d_in[2];
    const float* mx  = (const float*)d_in[3];
    float* out = (float*)d_out;
    const int nrows = in_sizes[0] / 16;        // 524288
    const int blocks = (nrows + 255) / 256;    // 2048 blocks x 4 waves x 64 rows
    qlin_kernel<<<blocks, 256, 0, stream>>>(in, wgt, mn, mx, out, nrows);
}